// Round 10
// baseline (1899.789 us; speedup 1.0000x reference)
//
#include <hip/hip_runtime.h>

// Decoder GRU, B=128 T=512 X=64 H=256, skip runtime (skip==0 -> generic
// path).  Round 16: TWO batches per WG to fill latency bubbles.
//
// R13-R15 established: step = 4870 cyc of which VALU issue ~1460 (VALUBusy
// 30% matches inst count), LDS pipe ~1600, and ~2500 cyc are dependency/
// latency bubbles immune to conflict/barrier/byte-count fixes.  Two waves
// per SIMD of identical lock-stepped work cannot fill each other's holes.
// Fix: each WG processes 2 batches.  Weights are batch-independent -> the
// 192 resident weight regs and the 128 KB wn LDS stream are SHARED (each
// wn uint4 read once, dotted with both batches' h), while the A/B dot
// chains are fully independent ILP that fills every load-wait bubble.
// Grid 64 WGs; per-CU/step VALU ~2400, LDS ~2300 -> step ~3000-3500 on 64
// CUs if the bubble thesis holds (~640-750 us); ~2x step if resource-bound
// (decisive A/B).  State duplicated per batch; skip-ring = fp16 pk2(hA,hB)
// (one broadcast read serves both; +1 fp16 rounding on skip operand, ~2^-11,
// well under the stable 0.0156 absmax).  Verified pieces kept: 1 lgkm-only
// barrier/step, PROJ-dots-first, HIW/PTW padded layouts (0 conflicts),
// DPP quad reduces, waves_per_eu(2,2) residency.
typedef _Float16 h2_t __attribute__((ext_vector_type(2)));

constexpr int T_ = 512;
constexpr int X_ = 64;
constexpr int H_ = 256;
constexpr int NWG = 64;   // 2 batches per WG, 1 WG/CU
constexpr int NT = 512;   // 8 waves = 2/EU
constexpr int RS = 16;    // ring slots; lookback 2*skip, OK for skip <= 7

// fp16 weight image in d_ws (uint4 units), all [u][t] with t = threadIdx:
//   u  0..31 : W_hh gates r,z   (g=u>>4, j=u&15; c=t>>1, kh=t&1)
//   u 32..47 : W_hh gate n      (j=u-32)
//   u 48..59 : W_ih 3 gates     (g=(u-48)>>2, j=(u-48)&3)
//   u 60..63 : W_out            (j=u-60; xc=t>>3, sl=t&7)
constexpr int G_TOTAL = 64 * NT;  // 32768 uint4 = 512 KB

__device__ __forceinline__ float sigmoid_f(float x) {
  float e = __expf(fminf(-x, 80.f));
  return 1.f / (1.f + e);
}
__device__ __forceinline__ float tanh_f(float x) {
  float e = __expf(fminf(-2.f * x, 80.f));
  return (1.f - e) / (1.f + e);
}

__device__ __forceinline__ unsigned pk2(float a, float b) {
  h2_t v;
  v[0] = (_Float16)a;
  v[1] = (_Float16)b;
  return __builtin_bit_cast(unsigned, v);
}
__device__ __forceinline__ uint4 pk8(const float* s) {
  return make_uint4(pk2(s[0], s[1]), pk2(s[2], s[3]), pk2(s[4], s[5]),
                    pk2(s[6], s[7]));
}

// fp16-pair dot with fp32 accumulate (v_dot2_f32_f16)
__device__ __forceinline__ float dotp(unsigned w, unsigned h, float acc) {
  h2_t wv = __builtin_bit_cast(h2_t, w);
  h2_t hv = __builtin_bit_cast(h2_t, h);
#if __has_builtin(__builtin_amdgcn_fdot2)
  return __builtin_amdgcn_fdot2(wv, hv, acc, false);
#else
  acc = fmaf((float)wv[0], (float)hv[0], acc);
  return fmaf((float)wv[1], (float)hv[1], acc);
#endif
}
__device__ __forceinline__ float dotq(uint4 w, uint4 h, float acc) {
  acc = dotp(w.x, h.x, acc);
  acc = dotp(w.y, h.y, acc);
  acc = dotp(w.z, h.z, acc);
  acc = dotp(w.w, h.w, acc);
  return acc;
}

// DPP quad_perm: xor1 = 0xB1, xor2 = 0x4E (VALU-only lane exchange)
__device__ __forceinline__ float dpp_xor1(float x) {
  int v = __builtin_amdgcn_update_dpp(0, __builtin_bit_cast(int, x), 0xB1,
                                      0xF, 0xF, true);
  return __builtin_bit_cast(float, v);
}
__device__ __forceinline__ float dpp_xor2(float x) {
  int v = __builtin_amdgcn_update_dpp(0, __builtin_bit_cast(int, x), 0x4E,
                                      0xF, 0xF, true);
  return __builtin_bit_cast(float, v);
}

// Main-loop barrier: LDS-only drain, no vmcnt (out[] stores never read back)
__device__ __forceinline__ void bar_lds() {
  asm volatile("s_waitcnt lgkmcnt(0)\n\ts_barrier" ::: "memory");
}

// One-time fp32 -> fp16 pack + transpose (identical to R14).
__global__ void prep_kernel(const float* __restrict__ Wih,
                            const float* __restrict__ Whh,
                            const float* __restrict__ Wout,
                            uint4* __restrict__ G) {
  int id = blockIdx.x * 256 + threadIdx.x;
  if (id >= G_TOTAL) return;
  int t = id & (NT - 1), u = id >> 9;
  int c = t >> 1, kh = t & 1;
  if (u < 32) {  // W_hh r,z
    int g = u >> 4, j = u & 15;
    G[id] = pk8(Whh + (size_t)(g * 256 + c) * H_ + kh * 128 + j * 8);
  } else if (u < 48) {  // W_hh n
    int j = u - 32;
    G[id] = pk8(Whh + (size_t)(512 + c) * H_ + kh * 128 + j * 8);
  } else if (u < 60) {  // W_ih
    int v = u - 48, g = v >> 2, j = v & 3;
    G[id] = pk8(Wih + (size_t)(g * 256 + c) * X_ + kh * 32 + j * 8);
  } else {  // W_out
    int j = u - 60, xc = t >> 3, sl = t & 7;
    G[id] = pk8(Wout + (size_t)xc * H_ + sl * 32 + j * 8);
  }
}

// padded pt2 word index (8 sl-blocks x 36 words, disjoint bank quads)
#define PTW(cp) (((cp) >> 4) * 36 + ((cp)&15))
// padded hid2 word index (kh=1 half at word 68, disjoint banks)
#define HIW(w) ((w) + (((w) >> 6) << 2))

// ---- per-step building blocks ----

#define GATES2(p, i, hnA, hnB)                                               \
  float hnA, hnB;                                                            \
  {                                                                          \
    float arA = 0, azA = 0, anA = 0, niA = 0;                                \
    float arB = 0, azB = 0, anB = 0, niB = 0;                                \
    const uint4* hA4 = ((const uint4*)hid2A[p]) + kh * 17;                   \
    const uint4* hB4 = ((const uint4*)hid2B[p]) + kh * 17;                   \
    _Pragma("unroll") for (int j = 0; j < 16; ++j) {                         \
      uint4 hA = hA4[j], hB = hB4[j]; /* 2-addr broadcasts */                \
      uint4 wn = wn4[j * NT + t];     /* shared by both batches */           \
      arA = dotq(whh_rz[j], hA, arA);                                        \
      arB = dotq(whh_rz[j], hB, arB);                                        \
      azA = dotq(whh_rz[16 + j], hA, azA);                                   \
      azB = dotq(whh_rz[16 + j], hB, azB);                                   \
      anA = dotq(wn, hA, anA);                                               \
      anB = dotq(wn, hB, anB);                                               \
    }                                                                        \
    const uint4* xA4 = ((const uint4*)xtA[p]) + kh * 4;                      \
    const uint4* xB4 = ((const uint4*)xtB[p]) + kh * 4;                      \
    _Pragma("unroll") for (int j = 0; j < 4; ++j) {                          \
      uint4 xa = xA4[j], xb = xB4[j];                                        \
      arA = dotq(wih[j], xa, arA);                                           \
      arB = dotq(wih[j], xb, arB);                                           \
      azA = dotq(wih[4 + j], xa, azA);                                       \
      azB = dotq(wih[4 + j], xb, azB);                                       \
      niA = dotq(wih[8 + j], xa, niA);                                       \
      niB = dotq(wih[8 + j], xb, niB);                                       \
    }                                                                        \
    arA += dpp_xor1(arA);                                                    \
    azA += dpp_xor1(azA);                                                    \
    anA += dpp_xor1(anA);                                                    \
    niA += dpp_xor1(niA);                                                    \
    arB += dpp_xor1(arB);                                                    \
    azB += dpp_xor1(azB);                                                    \
    anB += dpp_xor1(anB);                                                    \
    niB += dpp_xor1(niB);                                                    \
    float rA = sigmoid_f(arA + bsr), zA = sigmoid_f(azA + bsz);              \
    float nA = tanh_f(niA + bin_ + rA * (anA + bhn_));                       \
    hnA = fmaf(zA, hidA - nA, nA);                                           \
    float rB = sigmoid_f(arB + bsr), zB = sigmoid_f(azB + bsz);              \
    float nB = tanh_f(niB + bin_ + rB * (anB + bhn_));                       \
    hnB = fmaf(zB, hidB - nB, nB);                                           \
    if (kh == 0) ringAB[(i) & (RS - 1)][c] = pk2(hnA, hnB);                  \
  }

#define PROJ_DOTS(p)                                                         \
  float faA = 0, faB = 0;                                                    \
  {                                                                          \
    const uint4* pA4 = (const uint4*)&pt2A[p][sl * 36];                      \
    const uint4* pB4 = (const uint4*)&pt2B[p][sl * 36];                      \
    _Pragma("unroll") for (int j = 0; j < 4; ++j) {                          \
      faA = dotq(wout[j], pA4[j], faA);                                      \
      faB = dotq(wout[j], pB4[j], faB);                                      \
    }                                                                        \
  }

#define PROJ_FIN2(q, i)                                                      \
  {                                                                          \
    faA += dpp_xor1(faA);                                                    \
    faA += dpp_xor2(faA);                                                    \
    faA += __shfl_xor(faA, 4);                                               \
    faB += dpp_xor1(faB);                                                    \
    faB += dpp_xor2(faB);                                                    \
    faB += __shfl_xor(faB, 4);                                               \
    float oA = faA + bo, oB = faB + bo;                                      \
    if (sl == 0) {                                                           \
      out[obA + (size_t)(i)*X_ + xc] = oA;                                   \
      out[obB + (size_t)(i)*X_ + xc] = oB;                                   \
    }                                                                        \
    float ooA = __shfl_xor(oA, 8), ooB = __shfl_xor(oB, 8);                  \
    if ((t & 15) == 0) {                                                     \
      xtA[q][t >> 4] = pk2(oA, ooA);                                         \
      xtB[q][t >> 4] = pk2(oB, ooB);                                         \
    }                                                                        \
  }

// Main-loop step (i >= 2*skip, skip >= 1): pt2*[p] made at step i-1; PROJ
// dots are independent of GATES(i) -> issue first to fill load latency.
#define MSTEP2(i, p, q)                                                      \
  {                                                                          \
    PROJ_DOTS(p)                                                             \
    GATES2(p, i, hnA, hnB)                                                   \
    PROJ_FIN2(q, i)                                                          \
    if ((i) + 1 < T_) {                                                      \
      unsigned rw = ringAB[((i) + 1 - 2 * skip) & (RS - 1)][c];              \
      h2_t rv = __builtin_bit_cast(h2_t, rw);                                \
      float sgA = (float)rv[0], sgB = (float)rv[1];                          \
      float m0v = m0f[(i) + 1], m1v = m1f[(i) + 1];                          \
      float hidnA = fmaf(m0v, hnA, m1v * sgA);                               \
      float hidnB = fmaf(m0v, hnB, m1v * sgB);                               \
      float ptnA = hnA + sgA, ptnB = hnB + sgB;                              \
      hidA = hidnA;                                                          \
      hidB = hidnB;                                                          \
      float hoA = dpp_xor2(hidnA), poA = dpp_xor2(ptnA);                     \
      float hoB = dpp_xor2(hidnB), poB = dpp_xor2(ptnB);                     \
      if ((t & 3) == 0) {                                                    \
        int w = t >> 2;                                                      \
        hid2A[q][HIW(w)] = pk2(hidnA, hoA);                                  \
        pt2A[q][PTW(w)] = pk2(ptnA, poA);                                    \
        hid2B[q][HIW(w)] = pk2(hidnB, hoB);                                  \
        pt2B[q][PTW(w)] = pk2(ptnB, poB);                                    \
      }                                                                      \
    }                                                                        \
    bar_lds();                                                               \
  }

__global__ __attribute__((amdgpu_flat_work_group_size(NT, NT),
                          amdgpu_waves_per_eu(2, 2))) void decoder_kernel(
    const float* __restrict__ h_enc, const float* __restrict__ b_ih,
    const float* __restrict__ b_hh, const float* __restrict__ b_out,
    const int* __restrict__ mask0, const int* __restrict__ mask1,
    const int* __restrict__ skipp, const uint4* __restrict__ G,
    float* __restrict__ out) {
  __shared__ alignas(16) uint4 wn4[16 * NT];        // 128 KB W_hh n [u][t]
  __shared__ alignas(16) unsigned ringAB[RS][H_];   // 16 KB fp16 pk2(hA,hB)
  __shared__ alignas(16) unsigned hid2A[2][136];    // fp16 hidden, kh-padded
  __shared__ alignas(16) unsigned hid2B[2][136];
  __shared__ alignas(16) unsigned pt2A[2][8 * 36];  // fp16 h_prev+skip
  __shared__ alignas(16) unsigned pt2B[2][8 * 36];
  __shared__ alignas(16) unsigned xtA[2][X_ / 2];   // fp16 x feedback
  __shared__ alignas(16) unsigned xtB[2][X_ / 2];
  __shared__ float m0f[T_], m1f[T_];                // 4 KB masks
  // total: 131072+16384+2*1088+2*2304+2*256+4096 = 158848 B (155.1 KB)

  const int t = threadIdx.x;
  const int bA = 2 * blockIdx.x, bB = bA + 1;
  const int c = t >> 1, kh = t & 1;   // gate role: column, k-half
  const int xc = t >> 3, sl = t & 7;  // projection role
  const size_t obA = (size_t)bA * T_ * X_;
  const size_t obB = (size_t)bB * T_ * X_;

  // ---- resident weight registers: 48 uint4 = 192 regs/thread (shared) ----
  uint4 whh_rz[32];  // r,z gates, 128 k each (AGPR-resident)
  uint4 wih[12];     // 3 gates x 32 k
  uint4 wout[4];     // 32 k-slice of own xc column
#pragma unroll
  for (int u = 0; u < 32; ++u) whh_rz[u] = G[u * NT + t];
#pragma unroll
  for (int u = 0; u < 12; ++u) wih[u] = G[(48 + u) * NT + t];
#pragma unroll
  for (int u = 0; u < 4; ++u) wout[u] = G[(60 + u) * NT + t];

  // ---- LDS: n-gate weights + masks ----
#pragma unroll
  for (int u = 0; u < 16; ++u) wn4[u * NT + t] = G[(32 + u) * NT + t];
  m0f[t] = (float)mask0[t];
  m1f[t] = (float)mask1[t];

  const int skip = skipp[0];
  const int i0 = (skip == 0) ? T_ : ((2 * skip < T_) ? 2 * skip : T_);

  const float bsr = b_ih[c] + b_hh[c];
  const float bsz = b_ih[H_ + c] + b_hh[H_ + c];
  const float bin_ = b_ih[2 * H_ + c];
  const float bhn_ = b_hh[2 * H_ + c];
  const float bo = b_out[xc];

  float hpA = h_enc[(size_t)bA * H_ + c];
  float hpB = h_enc[(size_t)bB * H_ + c];
  const float m00 = (float)mask0[0];
  float hidA = m00 * hpA, hidB = m00 * hpB;  // hidden(0); skip_g(0) == 0
  float hpsA = hpA, hpsB = hpB;              // h_prev(0) = h_enc
  {
    float hoA = dpp_xor2(hidA), hoB = dpp_xor2(hidB);
    if ((t & 3) == 0) {
      hid2A[0][HIW(t >> 2)] = pk2(hidA, hoA);
      hid2B[0][HIW(t >> 2)] = pk2(hidB, hoB);
    }
  }
  if (t < X_ / 2) {
    xtA[0][t] = 0u;  // GO token
    xtB[0][t] = 0u;
  }
  __syncthreads();

  // ---- prologue: generic 2-barrier steps for i < 2*skip ----
  for (int i = 0; i < i0; ++i) {
    const int p = i & 1, q = p ^ 1;
    GATES2(p, i, hnA, hnB)
    {
      int ppos = (i < skip) ? 2 * i + 1 : i - skip;
      bool pz = ppos < skip;
      int pi = ppos - skip;
      if (pi < 0) pi = 0;
      float spA, spB;
      if (pz) {
        spA = 0.f;
        spB = 0.f;
      } else if (pi == i) {
        spA = hnA;
        spB = hnB;
      } else {
        h2_t rv = __builtin_bit_cast(h2_t, ringAB[pi & (RS - 1)][c]);
        spA = (float)rv[0];
        spB = (float)rv[1];
      }
      float ptvA = hpsA + spA, ptvB = hpsB + spB;
      float poA = dpp_xor2(ptvA), poB = dpp_xor2(ptvB);
      if ((t & 3) == 0) {
        pt2A[p][PTW(t >> 2)] = pk2(ptvA, poA);
        pt2B[p][PTW(t >> 2)] = pk2(ptvB, poB);
      }
    }
    if (i + 1 < T_) {
      int i1 = i + 1;
      int pg = (i1 < skip) ? 2 * i1 : i1 - skip;
      bool gz = pg < skip;
      int gi = pg - skip;
      if (gi < 0) gi = 0;
      if (gi >= i1) gz = true;  // unwritten slot == reference zero init
      float sgA, sgB;
      if (gz) {
        sgA = 0.f;
        sgB = 0.f;
      } else if (gi == i) {
        sgA = hnA;
        sgB = hnB;
      } else {
        h2_t rv = __builtin_bit_cast(h2_t, ringAB[gi & (RS - 1)][c]);
        sgA = (float)rv[0];
        sgB = (float)rv[1];
      }
      float hidnA = m0f[i1] * hnA + m1f[i1] * sgA;
      float hidnB = m0f[i1] * hnB + m1f[i1] * sgB;
      hidA = hidnA;
      hidB = hidnB;
      float hoA = dpp_xor2(hidnA), hoB = dpp_xor2(hidnB);
      if ((t & 3) == 0) {
        hid2A[q][HIW(t >> 2)] = pk2(hidnA, hoA);
        hid2B[q][HIW(t >> 2)] = pk2(hidnB, hoB);
      }
      if (skip > 0 && i1 >= 2 * skip) {  // handoff into fused main loop
        h2_t rv = __builtin_bit_cast(h2_t, ringAB[(i1 - 2 * skip) & (RS - 1)][c]);
        float ptnA = hnA + (float)rv[0], ptnB = hnB + (float)rv[1];
        float poA = dpp_xor2(ptnA), poB = dpp_xor2(ptnB);
        if ((t & 3) == 0) {
          pt2A[q][PTW(t >> 2)] = pk2(ptnA, poA);
          pt2B[q][PTW(t >> 2)] = pk2(ptnB, poB);
        }
      }
    }
    hpsA = hnA;
    hpsB = hnB;
    __syncthreads();
    {
      PROJ_DOTS(p)
      PROJ_FIN2(q, i)
    }
    __syncthreads();
  }

  // ---- main loop: one lgkm-only barrier per step; i0 even -> parity static
#pragma unroll 1
  for (int i = i0; i < T_; i += 2) {
    MSTEP2(i, 0, 1)
    MSTEP2(i + 1, 1, 0)
  }
}

extern "C" void kernel_launch(void* const* d_in, const int* in_sizes, int n_in,
                              void* d_out, int out_size, void* d_ws,
                              size_t ws_size, hipStream_t stream) {
  (void)in_sizes; (void)n_in; (void)out_size; (void)ws_size;
  // d_in[0] = input [B,T,X] — unused by the reference computation.
  const float* h_enc = (const float*)d_in[1];
  const float* W_ih = (const float*)d_in[2];
  const float* W_hh = (const float*)d_in[3];
  const float* b_ih = (const float*)d_in[4];
  const float* b_hh = (const float*)d_in[5];
  const float* W_out = (const float*)d_in[6];
  const float* b_out = (const float*)d_in[7];
  const int* mask0 = (const int*)d_in[8];
  const int* mask1 = (const int*)d_in[9];
  const int* skipp = (const int*)d_in[10];
  float* out = (float*)d_out;
  uint4* G = (uint4*)d_ws;  // 512 KB fp16 weight image

  prep_kernel<<<dim3(G_TOTAL / 256), dim3(256), 0, stream>>>(W_ih, W_hh,
                                                             W_out, G);
  decoder_kernel<<<dim3(NWG), dim3(NT), 0, stream>>>(
      h_enc, b_ih, b_hh, b_out, mask0, mask1, skipp, G, out);
}

// Round 12
// 1163.751 us; speedup vs baseline: 1.6325x; 1.6325x over previous
//
#include <hip/hip_runtime.h>

// Decoder GRU, B=128 T=512 X=64 H=256, skip runtime (skip==0 -> generic
// path).  Round 18 = Round 17 with the PKQ macro fixed (do-while(0) so it
// is a single statement inside brace-less unrolled loops).
//
// R14/R16 accounting: step 4870 cyc = VALU 2950 (dot2_f32_f16 measured
// ~half-rate: 670 instr -> 2950 busy cyc) + LDS-unit ~2500 (per-CU, shared
// by 4 SIMDs; wn stream 128 b128 + broadcasts), nearly additive because
// barrier-locked waves load together then compute together.
// Fix (a): v_pk_fma_f16 (full-rate packed fp16) replaces dot2 -> VALU
// ~halves.  Precision: 4 split h2 accumulators per gate (8 partials x ~20
// terms, ~1e-3), combined via pk_add + fdot2({1,1}) into f32; biases added
// after the DPP kh-reduce (not before, to avoid double count).
// Fix (b): even waves run PROJ-dots->GATES, odd waves GATES->PROJ-dots
// (wave-uniform branch) so the shared LDS unit is fed continuously.
// Everything else byte-identical to R14 (1038 us, verified): resident
// whh_rz 32u4 + wih 12u4 + wout 4u4, wn-gate 128 KB LDS [u][t], HIW/PTW
// padded layouts (0 conflicts), lgkm-only main-loop barrier.
typedef _Float16 h2_t __attribute__((ext_vector_type(2)));

constexpr int T_ = 512;
constexpr int X_ = 64;
constexpr int H_ = 256;
constexpr int NWG = 128;  // 1 batch per WG, 1 WG/CU
constexpr int NT = 512;   // 8 waves = 2/EU
constexpr int RS = 16;    // ring slots; lookback 2*skip, OK for skip <= 7

// fp16 weight image in d_ws (uint4 units), all [u][t] with t = threadIdx:
//   u  0..31 : W_hh gates r,z   (g=u>>4, j=u&15; c=t>>1, kh=t&1)
//   u 32..47 : W_hh gate n      (j=u-32)
//   u 48..59 : W_ih 3 gates     (g=(u-48)>>2, j=(u-48)&3)
//   u 60..63 : W_out            (j=u-60; xc=t>>3, sl=t&7)
constexpr int G_TOTAL = 64 * NT;  // 32768 uint4 = 512 KB

__device__ __forceinline__ float sigmoid_f(float x) {
  float e = __expf(fminf(-x, 80.f));
  return 1.f / (1.f + e);
}
__device__ __forceinline__ float tanh_f(float x) {
  float e = __expf(fminf(-2.f * x, 80.f));
  return (1.f - e) / (1.f + e);
}

__device__ __forceinline__ unsigned pk2(float a, float b) {
  h2_t v;
  v[0] = (_Float16)a;
  v[1] = (_Float16)b;
  return __builtin_bit_cast(unsigned, v);
}
__device__ __forceinline__ uint4 pk8(const float* s) {
  return make_uint4(pk2(s[0], s[1]), pk2(s[2], s[3]), pk2(s[4], s[5]),
                    pk2(s[6], s[7]));
}

// fp16-pair dot with fp32 accumulate (v_dot2_f32_f16) -- used only for the
// final partial-combine (2 per accumulator set).
__device__ __forceinline__ float dotp(unsigned w, unsigned h, float acc) {
  h2_t wv = __builtin_bit_cast(h2_t, w);
  h2_t hv = __builtin_bit_cast(h2_t, h);
#if __has_builtin(__builtin_amdgcn_fdot2)
  return __builtin_amdgcn_fdot2(wv, hv, acc, false);
#else
  acc = fmaf((float)wv[0], (float)hv[0], acc);
  return fmaf((float)wv[1], (float)hv[1], acc);
#endif
}

// packed fp16 FMA (v_pk_fma_f16, full-rate)
__device__ __forceinline__ h2_t pkfma(unsigned w, unsigned h, h2_t acc) {
  h2_t wv = __builtin_bit_cast(h2_t, w);
  h2_t hv = __builtin_bit_cast(h2_t, h);
#if __has_builtin(__builtin_elementwise_fma)
  return __builtin_elementwise_fma(wv, hv, acc);
#else
  return wv * hv + acc;
#endif
}
// accumulate a uint4 (8 fp16 MACs) into a 4-way split h2 accumulator set.
// Single statement (do-while) so it is safe in brace-less loop bodies.
#define PKQ(W4, H4, A)                                                      \
  do {                                                                      \
    A[0] = pkfma((W4).x, (H4).x, A[0]);                                     \
    A[1] = pkfma((W4).y, (H4).y, A[1]);                                     \
    A[2] = pkfma((W4).z, (H4).z, A[2]);                                     \
    A[3] = pkfma((W4).w, (H4).w, A[3]);                                     \
  } while (0)

#define ONE2U 0x3C003C00u  // {1.0h, 1.0h}

// combine 4 h2 partials -> f32 (2 pk_add + 2 fdot2)
__device__ __forceinline__ float pks(const h2_t* A) {
  h2_t s0 = A[0] + A[1];
  h2_t s1 = A[2] + A[3];
  float f = dotp(__builtin_bit_cast(unsigned, s0), ONE2U, 0.f);
  return dotp(__builtin_bit_cast(unsigned, s1), ONE2U, f);
}

// DPP quad_perm: xor1 = 0xB1, xor2 = 0x4E (VALU-only lane exchange)
__device__ __forceinline__ float dpp_xor1(float x) {
  int v = __builtin_amdgcn_update_dpp(0, __builtin_bit_cast(int, x), 0xB1,
                                      0xF, 0xF, true);
  return __builtin_bit_cast(float, v);
}
__device__ __forceinline__ float dpp_xor2(float x) {
  int v = __builtin_amdgcn_update_dpp(0, __builtin_bit_cast(int, x), 0x4E,
                                      0xF, 0xF, true);
  return __builtin_bit_cast(float, v);
}

// Main-loop barrier: LDS-only drain, no vmcnt (out[] stores never read back)
__device__ __forceinline__ void bar_lds() {
  asm volatile("s_waitcnt lgkmcnt(0)\n\ts_barrier" ::: "memory");
}

// One-time fp32 -> fp16 pack + transpose (identical to R14).
__global__ void prep_kernel(const float* __restrict__ Wih,
                            const float* __restrict__ Whh,
                            const float* __restrict__ Wout,
                            uint4* __restrict__ G) {
  int id = blockIdx.x * 256 + threadIdx.x;
  if (id >= G_TOTAL) return;
  int t = id & (NT - 1), u = id >> 9;
  int c = t >> 1, kh = t & 1;
  if (u < 32) {  // W_hh r,z
    int g = u >> 4, j = u & 15;
    G[id] = pk8(Whh + (size_t)(g * 256 + c) * H_ + kh * 128 + j * 8);
  } else if (u < 48) {  // W_hh n
    int j = u - 32;
    G[id] = pk8(Whh + (size_t)(512 + c) * H_ + kh * 128 + j * 8);
  } else if (u < 60) {  // W_ih
    int v = u - 48, g = v >> 2, j = v & 3;
    G[id] = pk8(Wih + (size_t)(g * 256 + c) * X_ + kh * 32 + j * 8);
  } else {  // W_out
    int j = u - 60, xc = t >> 3, sl = t & 7;
    G[id] = pk8(Wout + (size_t)xc * H_ + sl * 32 + j * 8);
  }
}

// padded pt2 word index (8 sl-blocks x 36 words, disjoint bank quads)
#define PTW(cp) (((cp) >> 4) * 36 + ((cp)&15))
// padded hid2 word index (kh=1 half at word 68, disjoint banks)
#define HIW(w) ((w) + (((w) >> 6) << 2))

// ---- per-step bodies (assign pre-declared hn / fa; p,q compile-time) ----

#define GATES_BODY(p, i)                                                     \
  {                                                                          \
    h2_t Z2 = (h2_t)0;                                                       \
    h2_t AR[4] = {Z2, Z2, Z2, Z2}, AZ[4] = {Z2, Z2, Z2, Z2};                 \
    h2_t AN[4] = {Z2, Z2, Z2, Z2}, NI[4] = {Z2, Z2, Z2, Z2};                 \
    const uint4* h4 = ((const uint4*)hid2[p]) + kh * 17;                     \
    _Pragma("unroll") for (int j = 0; j < 16; ++j) {                         \
      uint4 hj = h4[j]; /* broadcast, disjoint banks */                      \
      uint4 wn = wn4[j * NT + t];                                            \
      PKQ(whh_rz[j], hj, AR);                                                \
      PKQ(whh_rz[16 + j], hj, AZ);                                           \
      PKQ(wn, hj, AN);                                                       \
    }                                                                        \
    const uint4* x4 = ((const uint4*)xt2[p]) + kh * 4;                       \
    _Pragma("unroll") for (int j = 0; j < 4; ++j) {                          \
      uint4 xa = x4[j];                                                      \
      PKQ(wih[j], xa, AR);                                                   \
      PKQ(wih[4 + j], xa, AZ);                                               \
      PKQ(wih[8 + j], xa, NI);                                               \
    }                                                                        \
    float ar = pks(AR), az = pks(AZ), anh = pks(AN), ni = pks(NI);           \
    ar += dpp_xor1(ar);                                                      \
    az += dpp_xor1(az);                                                      \
    anh += dpp_xor1(anh);                                                    \
    ni += dpp_xor1(ni);                                                      \
    float r = sigmoid_f(ar + bsr);                                           \
    float z = sigmoid_f(az + bsz);                                           \
    float n = tanh_f(ni + bin_ + r * (anh + bhn_));                          \
    hn = fmaf(z, hid_reg - n, n); /* (1-z)*n + z*hidden */                   \
    if (kh == 0) ring[(i) & (RS - 1)][c] = hn;                               \
  }

#define PROJ_DOTS_BODY(p)                                                    \
  {                                                                          \
    h2_t Z2 = (h2_t)0;                                                       \
    h2_t FA[4] = {Z2, Z2, Z2, Z2};                                           \
    const uint4* p4 = (const uint4*)&pt2[p][sl * 36];                        \
    _Pragma("unroll") for (int j = 0; j < 4; ++j) {                          \
      PKQ(wout[j], p4[j], FA);                                               \
    }                                                                        \
    fa = pks(FA);                                                            \
  }

#define PROJ_FIN(q, i)                                                       \
  {                                                                          \
    fa += dpp_xor1(fa);                                                      \
    fa += dpp_xor2(fa);                                                      \
    fa += __shfl_xor(fa, 4);                                                 \
    float o = fa + bo;                                                       \
    if (sl == 0) out[ob + (size_t)(i)*X_ + xc] = o;                          \
    float oo = __shfl_xor(o, 8);                                             \
    if ((t & 15) == 0) xt2[q][t >> 4] = pk2(o, oo);                          \
  }

// Main-loop step (i >= 2*skip, skip >= 1): pt2[p] made at step i-1; PROJ is
// independent of GATES(i).  Wave-parity stagger: even waves do PROJ dots
// first, odd waves GATES first -> the shared per-CU LDS unit stays fed.
#define MSTEP(i, p, q)                                                       \
  {                                                                          \
    float hn, fa;                                                            \
    if (weven) {                                                             \
      PROJ_DOTS_BODY(p)                                                      \
      GATES_BODY(p, i)                                                       \
    } else {                                                                 \
      GATES_BODY(p, i)                                                       \
      PROJ_DOTS_BODY(p)                                                      \
    }                                                                        \
    PROJ_FIN(q, i)                                                           \
    if ((i) + 1 < T_) {                                                      \
      float sgp = ring[((i) + 1 - 2 * skip) & (RS - 1)][c];                  \
      float hidn = m0f[(i) + 1] * hn + m1f[(i) + 1] * sgp;                   \
      float ptn = hn + sgp;                                                  \
      hid_reg = hidn;                                                        \
      float ho = dpp_xor2(hidn);                                             \
      float po = dpp_xor2(ptn);                                              \
      if ((t & 3) == 0) {                                                    \
        int w = t >> 2;                                                      \
        hid2[q][HIW(w)] = pk2(hidn, ho);                                     \
        pt2[q][PTW(w)] = pk2(ptn, po);                                       \
      }                                                                      \
    }                                                                        \
    bar_lds();                                                               \
  }

__global__ __attribute__((amdgpu_flat_work_group_size(NT, NT),
                          amdgpu_waves_per_eu(2, 2))) void decoder_kernel(
    const float* __restrict__ h_enc, const float* __restrict__ b_ih,
    const float* __restrict__ b_hh, const float* __restrict__ b_out,
    const int* __restrict__ mask0, const int* __restrict__ mask1,
    const int* __restrict__ skipp, const uint4* __restrict__ G,
    float* __restrict__ out) {
  __shared__ alignas(16) uint4 wn4[16 * NT];       // 128 KB W_hh n-gate [u][t]
  __shared__ float ring[RS][H_];                   // 16 KB h history (fp32)
  __shared__ alignas(16) unsigned hid2[2][136];    // fp16 hidden, kh-padded
  __shared__ alignas(16) unsigned pt2[2][8 * 36];  // fp16 h_prev+skip, padded
  __shared__ alignas(16) unsigned xt2[2][X_ / 2];  // fp16 x feedback pairs
  __shared__ float m0f[T_], m1f[T_];               // 4 KB masks

  const int t = threadIdx.x;
  const int b = blockIdx.x;
  const int c = t >> 1, kh = t & 1;   // gate role: column, k-half
  const int xc = t >> 3, sl = t & 7;  // projection role
  const bool weven = ((t >> 6) & 1) == 0;
  const size_t ob = (size_t)b * T_ * X_;

  // ---- resident weight registers: 48 uint4 = 192 regs/thread ----
  uint4 whh_rz[32];  // r,z gates, 128 k each (lands in AGPRs)
  uint4 wih[12];     // 3 gates x 32 k
  uint4 wout[4];     // 32 k-slice of own xc column
#pragma unroll
  for (int u = 0; u < 32; ++u) whh_rz[u] = G[u * NT + t];
#pragma unroll
  for (int u = 0; u < 12; ++u) wih[u] = G[(48 + u) * NT + t];
#pragma unroll
  for (int u = 0; u < 4; ++u) wout[u] = G[(60 + u) * NT + t];

  // ---- LDS: n-gate weights + masks ----
#pragma unroll
  for (int u = 0; u < 16; ++u) wn4[u * NT + t] = G[(32 + u) * NT + t];
  m0f[t] = (float)mask0[t];
  m1f[t] = (float)mask1[t];

  const int skip = skipp[0];
  const int i0 = (skip == 0) ? T_ : ((2 * skip < T_) ? 2 * skip : T_);

  const float bsr = b_ih[c] + b_hh[c];
  const float bsz = b_ih[H_ + c] + b_hh[H_ + c];
  const float bin_ = b_ih[2 * H_ + c];
  const float bhn_ = b_hh[2 * H_ + c];
  const float bo = b_out[xc];

  float hp = h_enc[(size_t)b * H_ + c];
  float hid_reg = (float)mask0[0] * hp;  // hidden(0); skip_g(0) == 0
  float hps_reg = hp;                    // h_prev(0) = h_enc
  {
    float ho = dpp_xor2(hid_reg);
    if ((t & 3) == 0) hid2[0][HIW(t >> 2)] = pk2(hid_reg, ho);
  }
  if (t < X_ / 2) xt2[0][t] = 0u;  // GO token
  __syncthreads();

  // ---- prologue: generic 2-barrier steps for i < 2*skip ----
  for (int i = 0; i < i0; ++i) {
    const int p = i & 1, q = p ^ 1;
    float hn, fa;
    GATES_BODY(p, i)
    {
      int ppos = (i < skip) ? 2 * i + 1 : i - skip;
      bool pz = ppos < skip;
      int pi = ppos - skip;
      if (pi < 0) pi = 0;
      float sp = pz ? 0.f : ((pi == i) ? hn : ring[pi & (RS - 1)][c]);
      float ptv = hps_reg + sp;
      float po = dpp_xor2(ptv);
      if ((t & 3) == 0) pt2[p][PTW(t >> 2)] = pk2(ptv, po);
    }
    if (i + 1 < T_) {
      int i1 = i + 1;
      int pg = (i1 < skip) ? 2 * i1 : i1 - skip;
      bool gz = pg < skip;
      int gi = pg - skip;
      if (gi < 0) gi = 0;
      if (gi >= i1) gz = true;  // unwritten slot == reference zero init
      float sg = gz ? 0.f : ((gi == i) ? hn : ring[gi & (RS - 1)][c]);
      float hidn = m0f[i1] * hn + m1f[i1] * sg;
      hid_reg = hidn;
      float ho = dpp_xor2(hidn);
      if ((t & 3) == 0) hid2[q][HIW(t >> 2)] = pk2(hidn, ho);
      if (skip > 0 && i1 >= 2 * skip) {  // handoff into fused main loop
        float sgp = ring[(i1 - 2 * skip) & (RS - 1)][c];
        float ptn = hn + sgp;
        float po2 = dpp_xor2(ptn);
        if ((t & 3) == 0) pt2[q][PTW(t >> 2)] = pk2(ptn, po2);
      }
    }
    hps_reg = hn;
    __syncthreads();
    PROJ_DOTS_BODY(p)
    PROJ_FIN(q, i)
    __syncthreads();
  }

  // ---- main loop: one lgkm-only barrier per step; i0 even -> parity static
#pragma unroll 1
  for (int i = i0; i < T_; i += 2) {
    MSTEP(i, 0, 1)
    MSTEP(i + 1, 1, 0)
  }
}

extern "C" void kernel_launch(void* const* d_in, const int* in_sizes, int n_in,
                              void* d_out, int out_size, void* d_ws,
                              size_t ws_size, hipStream_t stream) {
  (void)in_sizes; (void)n_in; (void)out_size; (void)ws_size;
  // d_in[0] = input [B,T,X] — unused by the reference computation.
  const float* h_enc = (const float*)d_in[1];
  const float* W_ih = (const float*)d_in[2];
  const float* W_hh = (const float*)d_in[3];
  const float* b_ih = (const float*)d_in[4];
  const float* b_hh = (const float*)d_in[5];
  const float* W_out = (const float*)d_in[6];
  const float* b_out = (const float*)d_in[7];
  const int* mask0 = (const int*)d_in[8];
  const int* mask1 = (const int*)d_in[9];
  const int* skipp = (const int*)d_in[10];
  float* out = (float*)d_out;
  uint4* G = (uint4*)d_ws;  // 512 KB fp16 weight image

  prep_kernel<<<dim3(G_TOTAL / 256), dim3(256), 0, stream>>>(W_ih, W_hh,
                                                             W_out, G);
  decoder_kernel<<<dim3(NWG), dim3(NT), 0, stream>>>(
      h_enc, b_ih, b_hh, b_out, mask0, mask1, skipp, G, out);
}